// Round 1
// baseline (205.749 us; speedup 1.0000x reference)
//
#include <hip/hip_runtime.h>
#include <hip/hip_bf16.h>

// BCNet fused pipeline, MI355X gfx950.
// Shapes: B=128, NO=36, Q=14, VD=2048, QD=1024, H=2048.
//   K1: q_[1792,2048]   = relu(q[1792,1024] @ Wq[2048,1024]^T + bq)        (bf16 -> ws)
//   K2: qw[128,2048]    = sum_q q_[b*14+q,:] * wh[q]                       (f32  -> ws)
//   K3: logits[4608,2048] = relu(v[4608,2048] @ Wv^T + bv) * qw[b,:] + bh  (bf16 -> ws)
//   K4: out[4608,2048]  = logits @ W2[2048,2048]^T + b2                    (f32  -> d_out)

typedef __attribute__((ext_vector_type(4))) float f32x4;
typedef __attribute__((ext_vector_type(8))) short short8;

#define LDS_STRIDE 40   // shorts per LDS row: 32 data + 8 pad (80B rows -> ~2-way max bank aliasing)

__device__ __forceinline__ short f2bf(float f) {
    union { float f; unsigned u; } x; x.f = f;
    unsigned u = x.u;
    unsigned r = (u + 0x7FFFu + ((u >> 16) & 1u)) >> 16;   // RN-even
    return (short)(r & 0xFFFFu);
}
__device__ __forceinline__ float bf2f(short s) {
    union { unsigned u; float f; } x; x.u = ((unsigned)(unsigned short)s) << 16;
    return x.f;
}

// C[M,N] = A[M,K] * B[N,K]^T with fused epilogue.
// EPI: 0 = relu(acc+bias[n])                      -> bf16
//      1 = relu(acc+bias[n]) * qw[row/36, n] + bh -> bf16
//      2 = acc + bias[n]                          -> f32
// A_BF16: A is bf16 (row-major [M,K]) else f32.  B is always f32.
template<int EPI, int A_BF16>
__global__ __launch_bounds__(256)
void gemm_bt(const void* __restrict__ Ap, const float* __restrict__ Bp,
             const float* __restrict__ bias, const float* __restrict__ qw,
             const float* __restrict__ bh_p,
             void* __restrict__ Cp, int M, int N, int K)
{
    __shared__ short lds[2][2][128 * LDS_STRIDE];   // [buf][A/B][row*stride] = 40 KB

    const int tid    = threadIdx.x;
    const int lane   = tid & 63;
    const int wid    = tid >> 6;      // 0..3
    const int wr     = wid >> 1;      // wave row 0..1 (64-row half)
    const int wc     = wid & 1;       // wave col 0..1 (64-col half)
    const int lrow   = lane & 15;
    const int lchunk = lane >> 4;     // 0..3 -> k-subchunk of 8

    const int row0 = blockIdx.x * 128;
    const int col0 = blockIdx.y * 128;

    // staging coords: thread covers rows (sr, sr+64), cols sc..sc+7 of the 128x32 tile
    const int sr = tid >> 2;          // 0..63
    const int sc = (tid & 3) * 8;     // 0,8,16,24

    f32x4 acc[4][4];
    #pragma unroll
    for (int i = 0; i < 4; ++i)
        #pragma unroll
        for (int j = 0; j < 4; ++j)
            acc[i][j] = (f32x4)0.0f;

    const int nk = K >> 5;

    f32x4  rA[4], rB[4];   // f32 staging regs (2 rows x 8 floats each matrix)
    short8 rAb[2];         // bf16-A staging regs

    auto load_tile = [&](int kt) {
        const int kc = kt * 32;
        if (A_BF16) {
            const short* A = (const short*)Ap;
            rAb[0] = *(const short8*)&A[(size_t)(row0 + sr)      * K + kc + sc];
            rAb[1] = *(const short8*)&A[(size_t)(row0 + 64 + sr) * K + kc + sc];
        } else {
            const float* A = (const float*)Ap;
            rA[0] = *(const f32x4*)&A[(size_t)(row0 + sr)      * K + kc + sc];
            rA[1] = *(const f32x4*)&A[(size_t)(row0 + sr)      * K + kc + sc + 4];
            rA[2] = *(const f32x4*)&A[(size_t)(row0 + 64 + sr) * K + kc + sc];
            rA[3] = *(const f32x4*)&A[(size_t)(row0 + 64 + sr) * K + kc + sc + 4];
        }
        rB[0] = *(const f32x4*)&Bp[(size_t)(col0 + sr)      * K + kc + sc];
        rB[1] = *(const f32x4*)&Bp[(size_t)(col0 + sr)      * K + kc + sc + 4];
        rB[2] = *(const f32x4*)&Bp[(size_t)(col0 + 64 + sr) * K + kc + sc];
        rB[3] = *(const f32x4*)&Bp[(size_t)(col0 + 64 + sr) * K + kc + sc + 4];
    };

    auto store_tile = [&](int b) {
        short* la = &lds[b][0][0];
        short* lb = &lds[b][1][0];
        if (A_BF16) {
            *(short8*)&la[(size_t)sr        * LDS_STRIDE + sc] = rAb[0];
            *(short8*)&la[(size_t)(64 + sr) * LDS_STRIDE + sc] = rAb[1];
        } else {
            short8 s0, s1;
            #pragma unroll
            for (int j = 0; j < 4; ++j) { s0[j] = f2bf(rA[0][j]); s0[4 + j] = f2bf(rA[1][j]); }
            #pragma unroll
            for (int j = 0; j < 4; ++j) { s1[j] = f2bf(rA[2][j]); s1[4 + j] = f2bf(rA[3][j]); }
            *(short8*)&la[(size_t)sr        * LDS_STRIDE + sc] = s0;
            *(short8*)&la[(size_t)(64 + sr) * LDS_STRIDE + sc] = s1;
        }
        short8 t0, t1;
        #pragma unroll
        for (int j = 0; j < 4; ++j) { t0[j] = f2bf(rB[0][j]); t0[4 + j] = f2bf(rB[1][j]); }
        #pragma unroll
        for (int j = 0; j < 4; ++j) { t1[j] = f2bf(rB[2][j]); t1[4 + j] = f2bf(rB[3][j]); }
        *(short8*)&lb[(size_t)sr        * LDS_STRIDE + sc] = t0;
        *(short8*)&lb[(size_t)(64 + sr) * LDS_STRIDE + sc] = t1;
    };

    auto compute = [&](int b) {
        const short* la = &lds[b][0][0];
        const short* lb = &lds[b][1][0];
        short8 af[4], bfv[4];
        #pragma unroll
        for (int mi = 0; mi < 4; ++mi)
            af[mi] = *(const short8*)&la[(wr * 64 + mi * 16 + lrow) * LDS_STRIDE + lchunk * 8];
        #pragma unroll
        for (int ni = 0; ni < 4; ++ni)
            bfv[ni] = *(const short8*)&lb[(wc * 64 + ni * 16 + lrow) * LDS_STRIDE + lchunk * 8];
        #pragma unroll
        for (int mi = 0; mi < 4; ++mi)
            #pragma unroll
            for (int ni = 0; ni < 4; ++ni)
                acc[mi][ni] = __builtin_amdgcn_mfma_f32_16x16x32_bf16(af[mi], bfv[ni], acc[mi][ni], 0, 0, 0);
    };

    // prologue
    load_tile(0);
    store_tile(0);
    __syncthreads();

    int buf = 0;
    for (int kt = 0; kt < nk; ++kt) {
        if (kt + 1 < nk) load_tile(kt + 1);     // issue next-tile global loads early
        compute(buf);                            // MFMA on current LDS buffer
        if (kt + 1 < nk) store_tile(buf ^ 1);    // vmcnt-waited by compiler, lands in other buffer
        __syncthreads();
        buf ^= 1;
    }

    // epilogue: C/D layout (verified): col = lane&15, row = (lane>>4)*4 + reg
    const float bhv = (EPI == 1) ? bh_p[0] : 0.0f;
    #pragma unroll
    for (int mi = 0; mi < 4; ++mi) {
        #pragma unroll
        for (int ni = 0; ni < 4; ++ni) {
            #pragma unroll
            for (int r = 0; r < 4; ++r) {
                const int row = row0 + wr * 64 + mi * 16 + lchunk * 4 + r;
                const int col = col0 + wc * 64 + ni * 16 + lrow;
                float val = acc[mi][ni][r];
                if (EPI == 0) {
                    val = fmaxf(val + bias[col], 0.0f);
                    ((short*)Cp)[(size_t)row * N + col] = f2bf(val);
                } else if (EPI == 1) {
                    val = fmaxf(val + bias[col], 0.0f);
                    const int b = row / 36;
                    val = val * qw[b * 2048 + col] + bhv;
                    ((short*)Cp)[(size_t)row * N + col] = f2bf(val);
                } else {
                    ((float*)Cp)[(size_t)row * N + col] = val + bias[col];
                }
            }
        }
    }
}

// qw[b,h] = sum_q bf2f(q_[b*14+q, h]) * wh[q]
__global__ __launch_bounds__(256)
void qw_reduce(const short* __restrict__ q_, const float* __restrict__ wh,
               float* __restrict__ qw)
{
    const int idx = blockIdx.x * 256 + threadIdx.x;   // 0 .. 128*2048-1
    const int b = idx >> 11;
    const int h = idx & 2047;
    float s = 0.0f;
    #pragma unroll
    for (int qq = 0; qq < 14; ++qq)
        s += bf2f(q_[(size_t)(b * 14 + qq) * 2048 + h]) * wh[qq];
    qw[idx] = s;
}

extern "C" void kernel_launch(void* const* d_in, const int* in_sizes, int n_in,
                              void* d_out, int out_size, void* d_ws, size_t ws_size,
                              hipStream_t stream)
{
    const float* v  = (const float*)d_in[0];   // [128,36,2048]
    const float* q  = (const float*)d_in[1];   // [128,14,1024]
    const float* Wv = (const float*)d_in[2];   // [2048,2048]
    const float* bv = (const float*)d_in[3];   // [2048]
    const float* Wq = (const float*)d_in[4];   // [2048,1024]
    const float* bq = (const float*)d_in[5];   // [2048]
    const float* wh = (const float*)d_in[6];   // [14]
    const float* bh = (const float*)d_in[7];   // scalar
    const float* W2 = (const float*)d_in[8];   // [2048,2048]
    const float* b2 = (const float*)d_in[9];   // [2048]
    float* out = (float*)d_out;                // [128,36,2048]

    char* ws = (char*)d_ws;
    short* q_ws   = (short*)ws;                           // 1792*2048*2 = 7,340,032 B
    float* qw     = (float*)(ws + 7340032);               // 128*2048*4  = 1,048,576 B
    short* logits = (short*)(ws + 7340032 + 1048576);     // 4608*2048*2 = 18,874,368 B
    // total ws use: 27,262,976 B

    // K1: q_ = relu(q @ Wq^T + bq)   M=1792, N=2048, K=1024
    gemm_bt<0, 0><<<dim3(1792 / 128, 2048 / 128), 256, 0, stream>>>(
        q, Wq, bq, nullptr, nullptr, q_ws, 1792, 2048, 1024);

    // K2: qw reduce
    qw_reduce<<<(128 * 2048) / 256, 256, 0, stream>>>(q_ws, wh, qw);

    // K3: logits = relu(v @ Wv^T + bv) * qw + bh   M=4608, N=2048, K=2048
    gemm_bt<1, 0><<<dim3(4608 / 128, 2048 / 128), 256, 0, stream>>>(
        v, Wv, bv, qw, bh, logits, 4608, 2048, 2048);

    // K4: out = logits @ W2^T + b2   M=4608, N=2048, K=2048
    gemm_bt<2, 1><<<dim3(4608 / 128, 2048 / 128), 256, 0, stream>>>(
        logits, W2, b2, nullptr, nullptr, out, 4608, 2048, 2048);
}

// Round 2
// 169.202 us; speedup vs baseline: 1.2160x; 1.2160x over previous
//
#include <hip/hip_runtime.h>
#include <hip/hip_bf16.h>

// BCNet fused pipeline, MI355X gfx950 — round 2: all-bf16 GEMMs, m97 structure.
// Shapes: B=128, NO=36, Q=14, VD=2048, QD=1024, H=2048.
//   C0: convert v,q,Wv,Wq,W2 f32 -> bf16 (ws)
//   K1: q_[1792,2048]   = relu(qb[1792,1024] @ Wqb^T + bq)                  (bf16 -> ws)
//   K2: qw[128,2048]    = sum_q q_[b*14+q,:] * wh[q]                        (f32  -> ws)
//   K3: logits[4608,2048] = relu(vb[4608,2048] @ Wvb^T + bv) * qw[b,:] + bh (bf16 -> ws)
//   K4: out[4608,2048]  = logits @ W2b^T + b2                               (f32  -> d_out)

typedef __attribute__((ext_vector_type(4))) float f32x4;
typedef __attribute__((ext_vector_type(8))) short short8;

__device__ __forceinline__ short f2bf(float f) {
    union { float f; unsigned u; } x; x.f = f;
    unsigned u = x.u;
    unsigned r = (u + 0x7FFFu + ((u >> 16) & 1u)) >> 16;   // RN-even
    return (short)(r & 0xFFFFu);
}
__device__ __forceinline__ float bf2f(short s) {
    union { unsigned u; float f; } x; x.u = ((unsigned)(unsigned short)s) << 16;
    return x.f;
}

__device__ __forceinline__ void gload_lds16(const short* g, short* l) {
    __builtin_amdgcn_global_load_lds(
        (const __attribute__((address_space(1))) unsigned int*)g,
        (__attribute__((address_space(3))) unsigned int*)l,
        16, 0, 0);
}

// f32 -> bf16 conversion, 8 elems/thread, grid-stride
__global__ __launch_bounds__(256)
void cvt_bf16(const float* __restrict__ in, short* __restrict__ out, int n)
{
    const int stride = gridDim.x * 256 * 8;
    for (int i = (blockIdx.x * 256 + threadIdx.x) * 8; i < n; i += stride) {
        f32x4 a = *(const f32x4*)&in[i];
        f32x4 b = *(const f32x4*)&in[i + 4];
        short8 s;
        #pragma unroll
        for (int j = 0; j < 4; ++j) { s[j] = f2bf(a[j]); s[4 + j] = f2bf(b[j]); }
        *(short8*)&out[i] = s;
    }
}

// C[M,N] = A[M,K] * B[N,K]^T, A,B bf16 row-major, fused epilogue.
// EPI: 0 = relu(acc+bias[n])                      -> bf16
//      1 = relu(acc+bias[n]) * qw[row/36, n] + bh -> bf16
//      2 = acc + bias[n]                          -> f32
// m97 structure: 128x128 tile, BK=32, linear LDS, global_load_lds width=16.
template<int EPI>
__global__ __launch_bounds__(256)
void gemm_bt(const short* __restrict__ Ab, const short* __restrict__ Bb,
             const float* __restrict__ bias, const float* __restrict__ qw,
             const float* __restrict__ bh_p,
             void* __restrict__ Cp, int M, int N, int K)
{
    __shared__ short ldsA[128 * 32];   // 8 KB, linear (global_load_lds needs linear dest)
    __shared__ short ldsB[128 * 32];   // 8 KB

    const int tid    = threadIdx.x;
    const int lane   = tid & 63;
    const int wid    = tid >> 6;      // 0..3
    const int wr     = wid >> 1;      // wave row 0..1
    const int wc     = wid & 1;       // wave col 0..1
    const int lrow   = lane & 15;
    const int lchunk = lane >> 4;     // 0..3

    const int row0 = blockIdx.x * 128;
    const int col0 = blockIdx.y * 128;

    // staging geometry: wave w issue i covers elements [w*1024 + i*512 + lane*8 .. +8)
    // of the 128x32 tile; row = w*32 + i*16 + (lane>>2), col = (lane&3)*8.
    const int s_r = (lane >> 2);          // 0..15
    const int s_c = (lane & 3) * 8;       // 0,8,16,24

    f32x4 acc[4][4];
    #pragma unroll
    for (int i = 0; i < 4; ++i)
        #pragma unroll
        for (int j = 0; j < 4; ++j)
            acc[i][j] = (f32x4)0.0f;

    const int nk = K >> 5;

    for (int kt = 0; kt < nk; ++kt) {
        const int kc = kt * 32;
        if (kt) __syncthreads();          // all waves done reading previous tile
        #pragma unroll
        for (int i = 0; i < 2; ++i) {
            const int r = wid * 32 + i * 16 + s_r;
            gload_lds16(&Ab[(size_t)(row0 + r) * K + kc + s_c],
                        &ldsA[wid * 1024 + i * 512]);
            gload_lds16(&Bb[(size_t)(col0 + r) * K + kc + s_c],
                        &ldsB[wid * 1024 + i * 512]);
        }
        __syncthreads();                  // compiler drains vmcnt before barrier

        short8 af[4], bfv[4];
        #pragma unroll
        for (int mi = 0; mi < 4; ++mi)
            af[mi] = *(const short8*)&ldsA[(wr * 64 + mi * 16 + lrow) * 32 + lchunk * 8];
        #pragma unroll
        for (int ni = 0; ni < 4; ++ni)
            bfv[ni] = *(const short8*)&ldsB[(wc * 64 + ni * 16 + lrow) * 32 + lchunk * 8];
        #pragma unroll
        for (int mi = 0; mi < 4; ++mi)
            #pragma unroll
            for (int ni = 0; ni < 4; ++ni)
                acc[mi][ni] = __builtin_amdgcn_mfma_f32_16x16x32_bf16(af[mi], bfv[ni], acc[mi][ni], 0, 0, 0);
    }

    // epilogue: C/D layout: col = lane&15, row = (lane>>4)*4 + reg
    const float bhv = (EPI == 1) ? bh_p[0] : 0.0f;
    #pragma unroll
    for (int mi = 0; mi < 4; ++mi) {
        #pragma unroll
        for (int ni = 0; ni < 4; ++ni) {
            #pragma unroll
            for (int r = 0; r < 4; ++r) {
                const int row = row0 + wr * 64 + mi * 16 + lchunk * 4 + r;
                const int col = col0 + wc * 64 + ni * 16 + lrow;
                float val = acc[mi][ni][r];
                if (EPI == 0) {
                    val = fmaxf(val + bias[col], 0.0f);
                    ((short*)Cp)[(size_t)row * N + col] = f2bf(val);
                } else if (EPI == 1) {
                    val = fmaxf(val + bias[col], 0.0f);
                    const int b = row / 36;
                    val = val * qw[b * 2048 + col] + bhv;
                    ((short*)Cp)[(size_t)row * N + col] = f2bf(val);
                } else {
                    ((float*)Cp)[(size_t)row * N + col] = val + bias[col];
                }
            }
        }
    }
}

// qw[b,h] = sum_q bf2f(q_[b*14+q, h]) * wh[q]
__global__ __launch_bounds__(256)
void qw_reduce(const short* __restrict__ q_, const float* __restrict__ wh,
               float* __restrict__ qw)
{
    const int idx = blockIdx.x * 256 + threadIdx.x;   // 0 .. 128*2048-1
    const int b = idx >> 11;
    const int h = idx & 2047;
    float s = 0.0f;
    #pragma unroll
    for (int qq = 0; qq < 14; ++qq)
        s += bf2f(q_[(size_t)(b * 14 + qq) * 2048 + h]) * wh[qq];
    qw[idx] = s;
}

extern "C" void kernel_launch(void* const* d_in, const int* in_sizes, int n_in,
                              void* d_out, int out_size, void* d_ws, size_t ws_size,
                              hipStream_t stream)
{
    const float* v  = (const float*)d_in[0];   // [128,36,2048]
    const float* q  = (const float*)d_in[1];   // [128,14,1024]
    const float* Wv = (const float*)d_in[2];   // [2048,2048]
    const float* bv = (const float*)d_in[3];   // [2048]
    const float* Wq = (const float*)d_in[4];   // [2048,1024]
    const float* bq = (const float*)d_in[5];   // [2048]
    const float* wh = (const float*)d_in[6];   // [14]
    const float* bh = (const float*)d_in[7];   // scalar
    const float* W2 = (const float*)d_in[8];   // [2048,2048]
    const float* b2 = (const float*)d_in[9];   // [2048]
    float* out = (float*)d_out;                // [128,36,2048]

    char* ws = (char*)d_ws;
    short* vb     = (short*)(ws);                  // 4608*2048*2 = 18,874,368
    short* Wvb    = (short*)(ws + 18874368);       // 2048*2048*2 =  8,388,608
    short* W2b    = (short*)(ws + 27262976);       // 2048*2048*2 =  8,388,608
    short* qb     = (short*)(ws + 35651584);       // 1792*1024*2 =  3,670,016
    short* Wqb    = (short*)(ws + 39321600);       // 2048*1024*2 =  4,194,304
    short* q_ws   = (short*)(ws + 43515904);       // 1792*2048*2 =  7,340,032
    float* qw     = (float*)(ws + 50855936);       // 128*2048*4  =  1,048,576
    short* logits = (short*)(ws + 51904512);       // 4608*2048*2 = 18,874,368
    // total ws use: 70,778,880 B

    auto cvt = [&](const float* src, short* dst, int n) {
        int blocks = (n / 8 + 255) / 256;
        if (blocks > 2048) blocks = 2048;
        cvt_bf16<<<blocks, 256, 0, stream>>>(src, dst, n);
    };

    cvt(q,  qb,  1792 * 1024);
    cvt(Wq, Wqb, 2048 * 1024);
    cvt(v,  vb,  4608 * 2048);
    cvt(Wv, Wvb, 2048 * 2048);
    cvt(W2, W2b, 2048 * 2048);

    // K1: q_ = relu(qb @ Wqb^T + bq)   M=1792, N=2048, K=1024
    gemm_bt<0><<<dim3(1792 / 128, 2048 / 128), 256, 0, stream>>>(
        qb, Wqb, bq, nullptr, nullptr, q_ws, 1792, 2048, 1024);

    // K2: qw reduce
    qw_reduce<<<(128 * 2048) / 256, 256, 0, stream>>>(q_ws, wh, qw);

    // K3: logits = relu(vb @ Wvb^T + bv) * qw + bh   M=4608, N=2048, K=2048
    gemm_bt<1><<<dim3(4608 / 128, 2048 / 128), 256, 0, stream>>>(
        vb, Wvb, bv, qw, bh, logits, 4608, 2048, 2048);

    // K4: out = logits @ W2b^T + b2   M=4608, N=2048, K=2048
    gemm_bt<2><<<dim3(4608 / 128, 2048 / 128), 256, 0, stream>>>(
        logits, W2b, b2, nullptr, nullptr, out, 4608, 2048, 2048);
}